// Round 5
// baseline (242.024 us; speedup 1.0000x reference)
//
#include <hip/hip_runtime.h>

// ---------------------------------------------------------------------------
// SelfAttention: B=4, S=2048, D=1024, fp32 in/out, causal, no 1/sqrt(d).
// fp16 MFMA (16x16x32), fp32 accumulate, fp32 softmax.
//
// R13 = R12 with the staging-publication race fixed. R12 left A(n).h1 in
// flight across the window boundary, but waves 4-7 read staged half 1 at
// EVERY phase (the wave's internal M-half != staged half) -> race, absmax
// 4.96. Fix: stage A as interleaved E={rows 0-63,128-191} / O={64-127,
// 192-255} regions matching the true read deadlines (B+A.E at P0, A.O at
// P1), with counted waits: P0 VMW(2) forces A(n).O; P3 VMW(2) AFTER the
// MFMA cluster forces B(n+1)+A(n+1).E. Never drains in the main loop.
// Queue algebra (per wave, FIFO):
//   window start: [A(n).O]=2
//   P0: +B(n+1).h0 ->4; VMW(2) retires A(n).O (read at P1, post-barrier).
//   P1: +B(n+1).h1 ->4.  P2: +A(n+1).E ->6.
//   P3: +A(n+1).O ->8; after MMQ, VMW(2) retires B.h0,B.h1,A.E = exactly
//   window n+1's P0 deadline; A(n+1).O stays in flight. Steady.
// Accumulation order identical to R9-R12 -> absmax must be 0.09765625.
//
// ws layout (MiB):
//   [0,32)    Q,K fp16 slabs; later P fp16 overlays (after scores read Q,K)
//   [32,48)   Vt fp16 (b,e,s) — written by QKV epilogue
//   [48,112)  S fp32 (4x2048x2048)
//   [48,64)   x_h fp16      (over S; dead before S written)
//   [64,70)   Wh  fp16 [3072,1024] (over S; dead before S written)
// ---------------------------------------------------------------------------

typedef _Float16 h8 __attribute__((ext_vector_type(8)));
typedef _Float16 h4 __attribute__((ext_vector_type(4)));
typedef float f32x4 __attribute__((ext_vector_type(4)));

#define BM 128
#define BN 128

__device__ __forceinline__ void gl_lds16(const _Float16* g, _Float16* l) {
    __builtin_amdgcn_global_load_lds(
        (const __attribute__((address_space(1))) void*)g,
        (__attribute__((address_space(3))) void*)l, 16, 0, 0);
}

#define SBAR __builtin_amdgcn_sched_barrier(0)
#define BARX do { SBAR; __builtin_amdgcn_s_barrier(); SBAR; } while (0)
#define VMW(n) do { SBAR; asm volatile("s_waitcnt vmcnt(" #n ")"); SBAR; } while (0)

// ---------------------------------------------------------------------------
// qkv256c: A = x_h [8192][1024], B = Wh [3072][1024], C = QKV slabs.
// LDS bases (halves): Abuf0@0, Abuf1@16384, Bbuf0@32768, Bbuf1@49152.
// Region [256 rows][64 halves]; (row, seg s) holds global seg s^(row&7)
// (XOR applied on the global source; row bases are ==0 mod 8 so the
// read-undo ap = (kgroup^(la&7))*8 is unchanged).
// B staged as halves h: rows h*128 + wv*16 + (l>>3) (+8 for op 2).
// A staged as E/O: rows (wv>>2)*128 + (wv&3)*16 + q*64 + (l>>3).
// ---------------------------------------------------------------------------

#define STB(gp, BB, h) do { \
    gl_lds16((gp) + (h) * 131072,        sm + (BB) + (h) * 8192 + wv * 1024); \
    gl_lds16((gp) + (h) * 131072 + 8192, sm + (BB) + (h) * 8192 + wv * 1024 + 512); } while (0)

#define STA(gp, AB, q) do { \
    gl_lds16((gp) + (q) * 65536,        sm + (AB) + aldb + (q) * 4096); \
    gl_lds16((gp) + (q) * 65536 + 8192, sm + (AB) + aldb + (q) * 4096 + 512); } while (0)

#define LDA4(AB, h, ap) do { _Pragma("unroll") \
    for (int i = 0; i < 4; i++) \
        af[i] = *(const h8*)&sm[(AB) + abase + (h) * 4096 + i * 1024 + (ap)]; } while (0)

#define LDB4(BB, ap) do { _Pragma("unroll") \
    for (int j = 0; j < 4; j++) \
        bf[j] = *(const h8*)&sm[(BB) + bbase + j * 1024 + (ap)]; } while (0)

#define MMQ(h) do { __builtin_amdgcn_s_setprio(1); _Pragma("unroll") \
    for (int i = 0; i < 4; i++) { _Pragma("unroll") \
        for (int j = 0; j < 4; j++) \
            acc[(h) * 4 + i][j] = __builtin_amdgcn_mfma_f32_16x16x32_f16( \
                af[i], bf[j], acc[(h) * 4 + i][j], 0, 0, 0); } \
    __builtin_amdgcn_s_setprio(0); } while (0)

// One window = one K-tile (4 phases). AB/BB: current buffers; AQ/BQ: other
// buffers (staging dest); sAp/sBp: per-thread staging src for tile n+1.
#define WIN(AB, BB, AQ, BQ, sAp, sBp, LAST) do { h8 af[4], bf[4]; \
    LDB4(BB, ap0); LDA4(AB, 0, ap0); \
    if (!(LAST)) { STB(sBp, BQ, 0); VMW(2); } else { VMW(0); } \
    BARX; MMQ(0); BARX; \
    LDA4(AB, 1, ap0); \
    if (!(LAST)) STB(sBp, BQ, 1); \
    BARX; MMQ(1); BARX; \
    LDB4(BB, ap1); LDA4(AB, 0, ap1); \
    if (!(LAST)) STA(sAp, AQ, 0); \
    BARX; MMQ(0); BARX; \
    LDA4(AB, 1, ap1); \
    if (!(LAST)) STA(sAp, AQ, 1); \
    BARX; MMQ(1); \
    if (!(LAST)) VMW(2); \
    BARX; \
} while (0)

__global__ __launch_bounds__(512, 2) void qkv256c(
    const _Float16* __restrict__ A, const _Float16* __restrict__ B,
    _Float16* __restrict__ C)
{
    __shared__ __align__(16) _Float16 sm[65536];   // 128 KiB

    // XCD-bijective swizzle (384 % 8 == 0)
    const int bid = blockIdx.x;
    const int wg = (bid & 7) * 48 + (bid >> 3);
    const int by = wg / 12, bx = wg % 12;
    const int m0 = by * 256, n0 = bx * 256;

    const int tid = threadIdx.x;
    const int l = tid & 63;
    const int wv = tid >> 6;

    // staging: lane l -> row +(l>>3), global seg (l&7)^((l>>3)&7)
    const int pseg = ((l & 7) ^ ((l >> 3) & 7)) * 8;
    const _Float16* gA =
        A + (size_t)(m0 + (wv >> 2) * 128 + (wv & 3) * 16 + (l >> 3)) * 1024 + pseg;
    const _Float16* gB = B + (size_t)(n0 + wv * 16 + (l >> 3)) * 1024 + pseg;
    const int aldb = (wv >> 2) * 8192 + (wv & 3) * 1024;  // A dest base (halves)

    // fragments
    const int la = l & 15, qd = l >> 4;
    const int wm = (wv >> 2) * 128;             // 2 M row-groups
    const int wn = (wv & 3) * 64;               // 4 N col-groups
    const int ap0 = ((qd) ^ (la & 7)) * 8;      // k-step 0 phys seg
    const int ap1 = ((4 + qd) ^ (la & 7)) * 8;  // k-step 1 phys seg
    const int abase = (wm + la) * 64;
    const int bbase = (wn + la) * 64;

    f32x4 acc[8][4];
    #pragma unroll
    for (int i = 0; i < 8; i++)
        #pragma unroll
        for (int j = 0; j < 4; j++)
            acc[i][j] = (f32x4){0.f, 0.f, 0.f, 0.f};

    // prologue: tile0 -> buf0 (B.h0, B.h1, A.E, A.O);
    // VMW(2) forces B0 + A0.E (P0 deadline), leaves A0.O in flight
    // (first read at window 0 P1; forced by window 0 P0's VMW(2)).
    STB(gB, 32768, 0); STB(gB, 32768, 1);
    STA(gA, 0, 0);     STA(gA, 0, 1);
    VMW(2);
    BARX;

    const _Float16* sA = gA + 64;   // staging src, tile 1
    const _Float16* sB = gB + 64;

    #pragma unroll 1
    for (int t = 0; t < 14; t += 2) {
        WIN(0, 32768, 16384, 49152, sA, sB, 0);            // even window: buf0
        WIN(16384, 49152, 0, 32768, sA + 64, sB + 64, 0);  // odd window: buf1
        sA += 128; sB += 128;
    }
    WIN(0, 32768, 16384, 49152, sA, sB, 0);                // window 14 (stages 15)
    WIN(16384, 49152, 0, 32768, sA, sB, 1);                // window 15 (LAST)

    // epilogue (verified R9 mapping): D col=la, row=qd*4+rr; acc[i] rows
    // wm+i*16. 3072/256=12 -> tiles never straddle slab boundaries.
    if (bx < 8) {
        // Q/K slabs, row-major [s][e] within slab, ld 1024
        #pragma unroll
        for (int i = 0; i < 8; i++) {
            const int m = m0 + wm + i * 16 + qd * 4;
            #pragma unroll
            for (int j = 0; j < 4; j++) {
                const int col = n0 + wn + j * 16 + la;
                const size_t base = (size_t)(col >> 10) * 8388608 + (col & 1023);
                #pragma unroll
                for (int rr = 0; rr < 4; rr++)
                    C[base + (size_t)(m + rr) * 1024] = (_Float16)acc[i][j][rr];
            }
        }
    } else {
        // V slab stored transposed: Vt (b, e, s); rr -> s contiguous
        _Float16* Vt = C + (size_t)2 * 8388608;
        #pragma unroll
        for (int i = 0; i < 8; i++) {
            const int m = m0 + wm + i * 16 + qd * 4;
            const int b = m >> 11;
            const int sl = m & 2047;
            _Float16* Vb = Vt + (size_t)b * 2097152 + sl;
            #pragma unroll
            for (int j = 0; j < 4; j++) {
                const int e = n0 - 2048 + wn + j * 16 + la;
                h4 vv = { (_Float16)acc[i][j][0], (_Float16)acc[i][j][1],
                          (_Float16)acc[i][j][2], (_Float16)acc[i][j][3] };
                *(h4*)(Vb + (size_t)e * 2048) = vv;
            }
        }
    }
}

// ---------------------------------------------------------------------------
// NT GEMM (R8 structure) kept for scores (SWZ=2) and PV (SWZ=3).
// ---------------------------------------------------------------------------
template<int SWZ, int OM, bool KLIM>
__global__ __launch_bounds__(256) void gemm_nt(
    const _Float16* __restrict__ A, const _Float16* __restrict__ B,
    void* __restrict__ Cp, int N, int K,
    size_t sAz, size_t sBz, size_t sCz)
{
    __shared__ __align__(16) char smem[32768];
    _Float16* As = (_Float16*)smem;              // 2 x 4096 halves (k-stages)
    _Float16* Bs = (_Float16*)(smem + 16384);    // 2 x 4096 halves

    int bx, by;
    if (SWZ == 1) {
        const int r = blockIdx.x & 7, q2 = blockIdx.x >> 3;
        bx = q2 >> 3;
        by = ((q2 & 7) << 3) | r;
    } else if (SWZ == 2) {
        const int r = blockIdx.x & 7, g = blockIdx.x >> 3;   // g in 0..16
        if (g <= r) { by = r;      bx = g; }
        else        { by = 15 - r; bx = g - (r + 1); }
    } else {                                      // SWZ == 3
        const int r = blockIdx.x & 7, g = blockIdx.x >> 3;   // g in 0..15
        by = (g & 1) ? (15 - r) : r;
        bx = g >> 1;
    }

    const int tid  = threadIdx.x;
    const int lane = tid & 63;
    const int wv   = tid >> 6;
    const int m0 = by * BM, n0 = bx * BN;
    const size_t z = blockIdx.z;

    const int lr = lane >> 2;
    const int lc = ((lane & 3) ^ ((lane >> 3) & 3)) * 8;
    const _Float16* pA0 = A + z * sAz + (size_t)(m0 + wv * 16 + lr) * K + lc;
    const _Float16* pA1 = pA0 + (size_t)64 * K;
    const _Float16* pB0 = B + z * sBz + (size_t)(n0 + wv * 16 + lr) * K + lc;
    const _Float16* pB1 = pB0 + (size_t)64 * K;
    _Float16* lA0 = As + wv * 512;
    _Float16* lA1 = As + (wv + 4) * 512;
    _Float16* lB0 = Bs + wv * 512;
    _Float16* lB1 = Bs + (wv + 4) * 512;

    const int la = lane & 15;
    const int qd = lane >> 4;
    const int wm = (wv >> 1) * 64;
    const int wn = (wv & 1) * 64;
    const int sg = (qd ^ ((la >> 1) & 3)) * 8;

    f32x4 acc[4][4];
    #pragma unroll
    for (int i = 0; i < 4; i++)
        #pragma unroll
        for (int j = 0; j < 4; j++)
            acc[i][j] = (f32x4){0.f, 0.f, 0.f, 0.f};

    const int kEnd = KLIM ? (m0 + BM) : K;

    for (int k0 = 0; k0 < kEnd; k0 += 64) {
        gl_lds16(pA0,      lA0);
        gl_lds16(pA1,      lA1);
        gl_lds16(pB0,      lB0);
        gl_lds16(pB1,      lB1);
        gl_lds16(pA0 + 32, lA0 + 4096);
        gl_lds16(pA1 + 32, lA1 + 4096);
        gl_lds16(pB0 + 32, lB0 + 4096);
        gl_lds16(pB1 + 32, lB1 + 4096);
        pA0 += 64; pA1 += 64; pB0 += 64; pB1 += 64;
        __syncthreads();

        #pragma unroll
        for (int s = 0; s < 2; s++) {
            h8 af[4], bf[4];
            #pragma unroll
            for (int i = 0; i < 4; i++)
                af[i] = *(const h8*)&As[s * 4096 + (wm + i * 16 + la) * 32 + sg];
            #pragma unroll
            for (int i = 0; i < 4; i++)
                bf[i] = *(const h8*)&Bs[s * 4096 + (wn + i * 16 + la) * 32 + sg];
            #pragma unroll
            for (int i = 0; i < 4; i++)
                #pragma unroll
                for (int j = 0; j < 4; j++)
                    acc[i][j] = __builtin_amdgcn_mfma_f32_16x16x32_f16(af[i], bf[j], acc[i][j], 0, 0, 0);
        }
        __syncthreads();
    }

    if (OM == 2) {
        _Float16* C = (_Float16*)Cp;
        if (n0 < 2048) {
            #pragma unroll
            for (int i = 0; i < 4; i++)
                #pragma unroll
                for (int j = 0; j < 4; j++) {
                    const int col  = n0 + wn + j * 16 + la;
                    const size_t base = (size_t)(col >> 10) * 8388608 + (col & 1023);
                    #pragma unroll
                    for (int rr = 0; rr < 4; rr++)
                        C[base + (size_t)(m0 + wm + i * 16 + qd * 4 + rr) * 1024] =
                            (_Float16)acc[i][j][rr];
                }
        } else {
            _Float16* Vt = C + (size_t)2 * 8388608;
            #pragma unroll
            for (int i = 0; i < 4; i++) {
                const int m  = m0 + wm + i * 16 + qd * 4;
                const int b  = m >> 11;
                const int sl = m & 2047;
                _Float16* Vb = Vt + (size_t)b * 2097152 + sl;
                #pragma unroll
                for (int j = 0; j < 4; j++) {
                    const int e = n0 - 2048 + wn + j * 16 + la;
                    h4 vv = { (_Float16)acc[i][j][0], (_Float16)acc[i][j][1],
                              (_Float16)acc[i][j][2], (_Float16)acc[i][j][3] };
                    *(h4*)(Vb + (size_t)e * 2048) = vv;
                }
            }
        }
    } else {
        float* C = (float*)Cp + z * sCz;
        #pragma unroll
        for (int i = 0; i < 4; i++)
            #pragma unroll
            for (int j = 0; j < 4; j++)
                #pragma unroll
                for (int rr = 0; rr < 4; rr++)
                    C[(size_t)(m0 + wm + i * 16 + qd * 4 + rr) * N + (n0 + wn + j * 16 + la)] =
                        acc[i][j][rr];
    }
}

// fused fp32->fp16: blocks [0,4096) convert x (8M), [4096,5632) convert W (3x1M)
__global__ __launch_bounds__(256) void cvt_all(
    const float* __restrict__ x, const float* __restrict__ Wq,
    const float* __restrict__ Wk, const float* __restrict__ Wv,
    _Float16* __restrict__ x_h, _Float16* __restrict__ Wh)
{
    const int bid = blockIdx.x;
    const float* src; _Float16* dst; size_t off;
    if (bid < 4096) {
        src = x; dst = x_h; off = (size_t)bid * 2048;
    } else {
        const int b2 = bid - 4096;
        const int w = b2 >> 9;
        src = (w == 0) ? Wq : ((w == 1) ? Wk : Wv);
        dst = Wh + (size_t)w * 1048576;
        off = (size_t)(b2 & 511) * 2048;
    }
    const size_t i = off + (size_t)threadIdx.x * 8;
    float4 a = *(const float4*)(src + i);
    float4 b = *(const float4*)(src + i + 4);
    h8 o = { (_Float16)a.x, (_Float16)a.y, (_Float16)a.z, (_Float16)a.w,
             (_Float16)b.x, (_Float16)b.y, (_Float16)b.z, (_Float16)b.w };
    *(h8*)(dst + i) = o;
}

// causal row softmax: S fp32 -> P fp16. Thread t owns cols 8t..8t+7.
__global__ __launch_bounds__(256) void softmax_causal(const float* __restrict__ S,
                                                      _Float16* __restrict__ P)
{
    const int idx = blockIdx.x;          // 0..8191
    const int q = idx & 2047;
    const float* Srow = S + (size_t)idx * 2048;
    _Float16* Prow = P + (size_t)idx * 2048;
    const int t = threadIdx.x;
    const int k0 = t * 8;
    const int lane = t & 63, wv = t >> 6;
    __shared__ float red[4];

    float v[8];
    const bool any = (k0 <= q);
    if (any) {
        float4 a = *(const float4*)(Srow + k0);
        float4 b = *(const float4*)(Srow + k0 + 4);
        v[0] = a.x; v[1] = a.y; v[2] = a.z; v[3] = a.w;
        v[4] = b.x; v[5] = b.y; v[6] = b.z; v[7] = b.w;
    }
    float mx = -3.4e38f;
    #pragma unroll
    for (int j = 0; j < 8; j++)
        if (any && k0 + j <= q) mx = fmaxf(mx, v[j]);
    #pragma unroll
    for (int o = 32; o > 0; o >>= 1) mx = fmaxf(mx, __shfl_down(mx, o, 64));
    if (lane == 0) red[wv] = mx;
    __syncthreads();
    const float mall = fmaxf(fmaxf(red[0], red[1]), fmaxf(red[2], red[3]));
    __syncthreads();

    float sum = 0.f;
    #pragma unroll
    for (int j = 0; j < 8; j++) {
        float e = (any && k0 + j <= q) ? __expf(v[j] - mall) : 0.f;
        v[j] = e;
        sum += e;
    }
    #pragma unroll
    for (int o = 32; o > 0; o >>= 1) sum += __shfl_down(sum, o, 64);
    if (lane == 0) red[wv] = sum;
    __syncthreads();
    const float inv = 1.f / (red[0] + red[1] + red[2] + red[3]);

    const int kceil = ((q >> 7) + 1) << 7;       // PV reads cols < kceil
    if (k0 < kceil) {
        h8 o = { (_Float16)(v[0] * inv), (_Float16)(v[1] * inv),
                 (_Float16)(v[2] * inv), (_Float16)(v[3] * inv),
                 (_Float16)(v[4] * inv), (_Float16)(v[5] * inv),
                 (_Float16)(v[6] * inv), (_Float16)(v[7] * inv) };
        *(h8*)(Prow + k0) = o;
    }
}

extern "C" void kernel_launch(void* const* d_in, const int* in_sizes, int n_in,
                              void* d_out, int out_size, void* d_ws, size_t ws_size,
                              hipStream_t stream) {
    const float* x  = (const float*)d_in[0];
    const float* Wq = (const float*)d_in[1];
    const float* Wk = (const float*)d_in[2];
    const float* Wv = (const float*)d_in[3];
    float* out = (float*)d_out;

    const size_t MiB = 1024 * 1024;
    char* ws = (char*)d_ws;
    _Float16* QKVh = (_Float16*)ws;                     // Q,K slabs + Vt at slab 2
    _Float16* Vt   = QKVh + (size_t)2 * 8388608;        // [32,48) MiB, (b,e,s)
    float*    S    = (float*)(ws + 48 * MiB);           // 64 MiB
    _Float16* x_h  = (_Float16*)(ws + 48 * MiB);        // 16 MiB (over S)
    _Float16* Wh   = (_Float16*)(ws + 64 * MiB);        // 6 MiB  (over S)
    _Float16* P    = (_Float16*)ws;                     // 32 MiB (over Q,K)

    const dim3 blk(256);

    // 0) fp32 -> fp16 conversions (one dispatch)
    cvt_all<<<dim3(5632), blk, 0, stream>>>(x, Wq, Wk, Wv, x_h, Wh);

    // 1) QKV fused, 256x256 m201-clone (race-fixed): M=8192, N=3072
    qkv256c<<<dim3(384), dim3(512), 0, stream>>>(x_h, Wh, QKVh);

    // 2) scores: balanced lower-triangle decode, 136 tiles/batch
    gemm_nt<2, 0, false><<<dim3(136, 1, 4), blk, 0, stream>>>(
        QKVh, QKVh + 8388608, S, 2048, 1024,
        (size_t)2097152, (size_t)2097152, (size_t)4194304);

    // 3) causal softmax rows -> P fp16 (over Q,K)
    softmax_causal<<<dim3(4 * 2048), blk, 0, stream>>>(S, P);

    // 4) out = P @ Vt^T, fp32 out, K clipped at m0+128, residue swizzle
    gemm_nt<3, 0, true><<<dim3(128, 1, 4), blk, 0, stream>>>(
        P, Vt, out, 1024, 2048,
        (size_t)4194304, (size_t)2097152, (size_t)2097152);
}